// Round 3
// baseline (19157.143 us; speedup 1.0000x reference)
//
#include <hip/hip_runtime.h>
#include <stdint.h>

// ---------------------------------------------------------------------------
// LSTM forward, T=2048 B=64 I=H=512.
// Phase 1: Xg = X @ [W_xf|W_xi|W_xo|W_xc]  (bf16 MFMA GEMM, m97-style tile)
// Phase 2: persistent recurrence kernel, 4 batch-groups x 64 hidden-groups,
//          W_h slices stationary in LDS. Cross-WG h exchange is SEQLOCK-style:
//          each h element is a 32-bit word [bf16 value | 16-bit step tag].
//          The poll IS the data load, BATCHED: one do/while issues all 32
//          words/lane (the wave's whole A-operand slice) back-to-back, so a
//          retry costs ONE L3 round trip, not four serialized ones.
//          Overwrite safety (fire-and-forget, no fences): WG stores tag t+2
//          only after validating tag t+1 from ALL producers, each of which
//          stored t+1 data-dependent on its step-t Cred reads -> no consumer
//          can still need a tag-t word when it is overwritten.
// (Resubmission of round-1 kernel: previous bench died to container infra,
//  no measurement was produced. Logic re-audited: no OOB, no deadlock.)
// ---------------------------------------------------------------------------

typedef __attribute__((ext_vector_type(8))) short short8;
typedef __attribute__((ext_vector_type(4))) float f32x4;

#define T_STEPS 2048
#define SLOT (64 * 512)  // words per h double-buffer slot

__device__ __forceinline__ unsigned short f2bf(float f) {
  unsigned int x = __float_as_uint(f);
  x += 0x7fffu + ((x >> 16) & 1u);   // RNE
  return (unsigned short)(x >> 16);
}
__device__ __forceinline__ float bf2f(unsigned short u) {
  return __uint_as_float(((unsigned int)u) << 16);
}
// async global->LDS, 16B per lane; lds base must be wave-uniform.
__device__ __forceinline__ void gl2lds16(const void* g, void* lds) {
  __builtin_amdgcn_global_load_lds(
      (const __attribute__((address_space(1))) void*)(uintptr_t)g,
      (__attribute__((address_space(3))) void*)(unsigned int)(uintptr_t)lds,
      16, 0, 0);
}

// --------------------------- phase 0: casts/packs ---------------------------

__global__ __launch_bounds__(256) void cast_x_kernel(
    const float* __restrict__ X, unsigned short* __restrict__ Xb) {
  long long i = ((long long)blockIdx.x * 256 + threadIdx.x) * 8;
  float4 a = *(const float4*)(X + i);
  float4 b = *(const float4*)(X + i + 4);
  union { short8 v; unsigned short u[8]; } o;
  o.u[0] = f2bf(a.x); o.u[1] = f2bf(a.y); o.u[2] = f2bf(a.z); o.u[3] = f2bf(a.w);
  o.u[4] = f2bf(b.x); o.u[5] = f2bf(b.y); o.u[6] = f2bf(b.z); o.u[7] = f2bf(b.w);
  *(short8*)(Xb + i) = o.v;
}

// Wt[n][k] = W_gate(n/512)[k][n%512]  (transposed, bf16)  n in [0,2048)
__global__ __launch_bounds__(256) void pack_w_kernel(
    const float* __restrict__ Wf, const float* __restrict__ Wi,
    const float* __restrict__ Wo, const float* __restrict__ Wc,
    unsigned short* __restrict__ Wt) {
  int n = blockIdx.x;
  int g = n >> 9, h = n & 511;
  const float* W = (g == 0) ? Wf : (g == 1) ? Wi : (g == 2) ? Wo : Wc;
  for (int k = threadIdx.x; k < 512; k += 256)
    Wt[(size_t)n * 512 + k] = f2bf(W[(size_t)k * 512 + h]);
}

// zero the tagged h double-buffer: word=0 -> value=bf16(0), tag=0 (step 0 valid)
__global__ __launch_bounds__(256) void init_kernel(unsigned int* hbuf) {
  int i = blockIdx.x * 256 + threadIdx.x;
  if (i < 2 * SLOT) hbuf[i] = 0u;
}

// --------------------------- phase 1: input GEMM ---------------------------
// A [131072,512] bf16 row-major; Bt [2048,512] bf16 (B transposed);
// C [131072,2048] bf16. 128x128 tile, BK=64, 4 waves in 2x2, 4x4 MFMA each.
__global__ __launch_bounds__(256) void gemm_xg_kernel(
    const unsigned short* __restrict__ A, const unsigned short* __restrict__ Bt,
    unsigned short* __restrict__ C) {
  __shared__ unsigned short As[128 * 64];
  __shared__ unsigned short Bs[128 * 64];
  const int tid = threadIdx.x;
  const int lane = tid & 63, wave = tid >> 6;
  const int bm = blockIdx.x, bn = blockIdx.y;
  const int wm = (wave & 1) * 64, wn = (wave >> 1) * 64;

  f32x4 acc[4][4];
#pragma unroll
  for (int i = 0; i < 4; ++i)
#pragma unroll
    for (int j = 0; j < 4; ++j) acc[i][j] = (f32x4){0.f, 0.f, 0.f, 0.f};

  for (int kt = 0; kt < 512; kt += 64) {
    __syncthreads();  // previous compute done before LDS overwrite
#pragma unroll
    for (int r = 0; r < 4; ++r) {
      int chunk = r * 256 + tid;          // [0,1024): row=chunk>>3, c8=chunk&7
      int row = chunk >> 3, c8 = chunk & 7;
      gl2lds16(A + ((size_t)(bm * 128 + row) * 512 + kt + c8 * 8),
               (void*)(As + (size_t)(r * 256 + wave * 64) * 8));
      gl2lds16(Bt + ((size_t)(bn * 128 + row) * 512 + kt + c8 * 8),
               (void*)(Bs + (size_t)(r * 256 + wave * 64) * 8));
    }
    __syncthreads();  // staging complete (vmcnt drained by barrier)
#pragma unroll
    for (int kc = 0; kc < 64; kc += 32) {
      const int ko = kc + (lane >> 4) * 8;
      short8 av[4], bv[4];
#pragma unroll
      for (int mt = 0; mt < 4; ++mt)
        av[mt] = *(const short8*)(As + (wm + mt * 16 + (lane & 15)) * 64 + ko);
#pragma unroll
      for (int nt = 0; nt < 4; ++nt)
        bv[nt] = *(const short8*)(Bs + (wn + nt * 16 + (lane & 15)) * 64 + ko);
#pragma unroll
      for (int mt = 0; mt < 4; ++mt)
#pragma unroll
        for (int nt = 0; nt < 4; ++nt)
          acc[mt][nt] = __builtin_amdgcn_mfma_f32_16x16x32_bf16(
              av[mt], bv[nt], acc[mt][nt], 0, 0, 0);
    }
  }
  const int q = lane >> 4, cidx = lane & 15;
#pragma unroll
  for (int mt = 0; mt < 4; ++mt)
#pragma unroll
    for (int nt = 0; nt < 4; ++nt)
#pragma unroll
      for (int r = 0; r < 4; ++r) {
        int row = wm + mt * 16 + q * 4 + r;  // C/D: col=lane&15, row=quad*4+reg
        int col = wn + nt * 16 + cidx;
        C[(size_t)(bm * 128 + row) * 2048 + bn * 128 + col] = f2bf(acc[mt][nt][r]);
      }
}

// --------------------------- phase 2: recurrence ---------------------------
// grid 256 = GB(4) x GH(64). WG (gb,gh): batch slice gb*16..+16, hidden slice
// gh*8..+8 (-> 32 W_h columns: 4 gates x 8). W_h slice transposed in LDS.
// h exchange: hbuf words are [bf16 h_t | t&0xffff]; slot t&1. Each wave
// poll-loads its ENTIRE 32-word/lane A-slice in one batch and retries until
// every embedded tag matches t (one L3 round trip per retry). Producer
// stores are fire-and-forget. Cred is double-buffered on t&1 so only one
// __syncthreads per step is needed; fast waves self-throttle on the next
// step's seqlock poll.
__global__ __launch_bounds__(256) void lstm_rec_kernel(
    const unsigned short* __restrict__ Xg,   // [T*64][2048] bf16
    const unsigned short* __restrict__ Wht,  // [2048][512] bf16 (row n = g*512+h)
    const float* __restrict__ b_f, const float* __restrict__ b_i,
    const float* __restrict__ b_o, const float* __restrict__ b_c,
    float* __restrict__ out, unsigned int* hbuf) {
  const int tid = threadIdx.x;
  const int lane = tid & 63, wave = tid >> 6;
  const int gb = blockIdx.x >> 6;
  const int gh = blockIdx.x & 63;

  __shared__ unsigned short Wl[32][520];   // [col=g*8+j][k], +8 pad: 2-way bank max
  __shared__ float Cred[2][4][16][33];     // per-wave partial C, dbuf by t&1

  for (int idx = tid; idx < 32 * 64; idx += 256) {
    int cc = idx >> 6, k8 = idx & 63;
    int n = (cc >> 3) * 512 + gh * 8 + (cc & 7);
    short8 v = *(const short8*)(Wht + (size_t)n * 512 + k8 * 8);
    *(short8*)(&Wl[cc][k8 * 8]) = v;
  }

  float creg = 0.f;
  float bias0 = 0.f, bias1 = 0.f, bias2 = 0.f, bias3 = 0.f;
  int bb = 0, jj = 0;
  if (tid < 128) {
    bb = tid >> 3; jj = tid & 7;
    int col = gh * 8 + jj;
    bias0 = b_f[col]; bias1 = b_i[col]; bias2 = b_o[col]; bias3 = b_c[col];
  }
  __syncthreads();

  const int m = lane & 15, quad = lane >> 4;

  for (int t = 0; t < T_STEPS; ++t) {
    // Xg loads issued early: independent of h_t, latency hidden under poll
    float xg0 = 0.f, xg1 = 0.f, xg2 = 0.f, xg3 = 0.f;
    if (tid < 128) {
      const unsigned short* xr =
          Xg + ((size_t)t * 64 + gb * 16 + bb) * 2048 + gh * 8 + jj;
      xg0 = bf2f(xr[0]); xg1 = bf2f(xr[512]); xg2 = bf2f(xr[1024]); xg3 = bf2f(xr[1536]);
    }
    const unsigned int tg = (unsigned int)t & 0xffffu;
    const unsigned int* hrow =
        hbuf + (size_t)(t & 1) * SLOT + (size_t)(gb * 16 + m) * 512 + wave * 128 +
        quad * 8;
    // ---- batched seqlock poll: all 32 words issued back-to-back ----
    unsigned int w[4][8];
    unsigned int bad;
    int tries = 0;
    do {
#pragma unroll
      for (int c = 0; c < 4; ++c) {
        const unsigned int* ap = hrow + c * 32;
#pragma unroll
        for (int u = 0; u < 8; ++u)
          w[c][u] = __hip_atomic_load(ap + u, __ATOMIC_RELAXED,
                                      __HIP_MEMORY_SCOPE_AGENT);
      }
      bad = 0u;
#pragma unroll
      for (int c = 0; c < 4; ++c)
#pragma unroll
        for (int u = 0; u < 8; ++u) bad |= (w[c][u] ^ tg);
      bad &= 0xffffu;
      if (bad && ++tries > 2) __builtin_amdgcn_s_sleep(1);  // contention backoff
    } while (bad != 0u);

    f32x4 acc0 = {0.f, 0.f, 0.f, 0.f}, acc1 = {0.f, 0.f, 0.f, 0.f};
#pragma unroll
    for (int c = 0; c < 4; ++c) {
      const int k = wave * 128 + c * 32 + quad * 8;
      union { short8 v; unsigned int u[4]; } au;
      au.u[0] = (w[c][0] >> 16) | (w[c][1] & 0xffff0000u);
      au.u[1] = (w[c][2] >> 16) | (w[c][3] & 0xffff0000u);
      au.u[2] = (w[c][4] >> 16) | (w[c][5] & 0xffff0000u);
      au.u[3] = (w[c][6] >> 16) | (w[c][7] & 0xffff0000u);
      short8 bfr0 = *(const short8*)(&Wl[m][k]);
      short8 bfr1 = *(const short8*)(&Wl[16 + m][k]);
      acc0 = __builtin_amdgcn_mfma_f32_16x16x32_bf16(au.v, bfr0, acc0, 0, 0, 0);
      acc1 = __builtin_amdgcn_mfma_f32_16x16x32_bf16(au.v, bfr1, acc1, 0, 0, 0);
    }
    const int pb = t & 1;
#pragma unroll
    for (int r = 0; r < 4; ++r) {
      Cred[pb][wave][quad * 4 + r][m] = acc0[r];
      Cred[pb][wave][quad * 4 + r][16 + m] = acc1[r];
    }
    __syncthreads();  // all partials of step t in Cred[pb]
    if (tid < 128) {
      float gf = Cred[pb][0][bb][jj] + Cred[pb][1][bb][jj] + Cred[pb][2][bb][jj] + Cred[pb][3][bb][jj];
      float gi = Cred[pb][0][bb][8+jj] + Cred[pb][1][bb][8+jj] + Cred[pb][2][bb][8+jj] + Cred[pb][3][bb][8+jj];
      float go = Cred[pb][0][bb][16+jj] + Cred[pb][1][bb][16+jj] + Cred[pb][2][bb][16+jj] + Cred[pb][3][bb][16+jj];
      float gc = Cred[pb][0][bb][24+jj] + Cred[pb][1][bb][24+jj] + Cred[pb][2][bb][24+jj] + Cred[pb][3][bb][24+jj];
      gf += bias0 + xg0; gi += bias1 + xg1; go += bias2 + xg2; gc += bias3 + xg3;
      float f  = 1.f / (1.f + __expf(-gf));
      float ii = 1.f / (1.f + __expf(-gi));
      float oo = 1.f / (1.f + __expf(-go));
      float ch = 1.f - 2.f / (1.f + __expf(2.f * gc));   // tanh
      creg = f * creg + ii * ch;
      float tc = 1.f - 2.f / (1.f + __expf(2.f * creg));
      float h = oo * tc;
      size_t orow = ((size_t)t * 64 + gb * 16 + bb) * 512 + gh * 8 + jj;
      out[orow] = h;
      // fire-and-forget tagged store: [bf16 h | t+1]; agent scope bypasses
      // the non-coherent per-XCD L2, lands at the L3 coherence point.
      unsigned int word =
          ((unsigned int)f2bf(h) << 16) | ((unsigned int)(t + 1) & 0xffffu);
      __hip_atomic_store(hbuf + (size_t)((t + 1) & 1) * SLOT +
                             (size_t)(gb * 16 + bb) * 512 + gh * 8 + jj,
                         word, __ATOMIC_RELAXED, __HIP_MEMORY_SCOPE_AGENT);
      if (t == T_STEPS - 1) {
        size_t base = (size_t)T_STEPS * 64 * 512;
        out[base + (size_t)(gb * 16 + bb) * 512 + gh * 8 + jj] = h;
        out[base + 64 * 512 + (size_t)(gb * 16 + bb) * 512 + gh * 8 + jj] = creg;
      }
    }
    // no second barrier: Cred is double-buffered; fast waves block on the
    // next step's seqlock poll until producers (incl. this WG's activation
    // threads) have stored tag t+1.
  }
}

// ------------------------------- launch ------------------------------------

extern "C" void kernel_launch(void* const* d_in, const int* in_sizes, int n_in,
                              void* d_out, int out_size, void* d_ws, size_t ws_size,
                              hipStream_t stream) {
  const float* X    = (const float*)d_in[0];
  const float* W_xf = (const float*)d_in[1];
  const float* W_hf = (const float*)d_in[2];
  const float* b_f  = (const float*)d_in[3];
  const float* W_xi = (const float*)d_in[4];
  const float* W_hi = (const float*)d_in[5];
  const float* b_i  = (const float*)d_in[6];
  const float* W_xo = (const float*)d_in[7];
  const float* W_ho = (const float*)d_in[8];
  const float* b_o  = (const float*)d_in[9];
  const float* W_xc = (const float*)d_in[10];
  const float* W_hc = (const float*)d_in[11];
  const float* b_c  = (const float*)d_in[12];
  float* out = (float*)d_out;

  char* ws = (char*)d_ws;
  unsigned short* Xb   = (unsigned short*)(ws + 0LL);           // 134,217,728 B (dead after gemm)
  unsigned short* Xg   = (unsigned short*)(ws + 134217728LL);   // 536,870,912 B
  unsigned short* Wxt  = (unsigned short*)(ws + 671088640LL);   //   2,097,152 B
  unsigned short* Wht  = (unsigned short*)(ws + 673185792LL);   //   2,097,152 B
  unsigned int* hbuf   = (unsigned int*)(ws + 0LL);             //     262,144 B (reuses Xb region)

  cast_x_kernel<<<dim3(32768), dim3(256), 0, stream>>>(X, Xb);
  pack_w_kernel<<<dim3(2048), dim3(256), 0, stream>>>(W_xf, W_xi, W_xo, W_xc, Wxt);
  pack_w_kernel<<<dim3(2048), dim3(256), 0, stream>>>(W_hf, W_hi, W_ho, W_hc, Wht);
  gemm_xg_kernel<<<dim3(1024, 16), dim3(256), 0, stream>>>(Xb, Wxt, Xg);
  // hbuf aliases Xb: init only after the GEMM has consumed Xb.
  init_kernel<<<dim3(256), dim3(256), 0, stream>>>(hbuf);
  lstm_rec_kernel<<<dim3(256), dim3(256), 0, stream>>>(Xg, Wht, b_f, b_i, b_o, b_c,
                                                       out, hbuf);
}

// Round 4
// 8609.189 us; speedup vs baseline: 2.2252x; 2.2252x over previous
//
#include <hip/hip_runtime.h>
#include <stdint.h>

// ---------------------------------------------------------------------------
// LSTM forward, T=2048 B=64 I=H=512.
// Phase 1: Xg = X @ [W_xf|W_xi|W_xo|W_xc]  (bf16 MFMA GEMM, m97-style tile)
// Phase 2: persistent recurrence, 64 WGs = 4 batch-groups x 16 hidden-groups.
//   - flag-based sync (measured best; seqlock-on-data refuted rounds 1-3)
//   - flags: 16 per group packed in ONE cacheline -> poll = 1 L3 request
//   - W_h slice lives in VGPRs (128/wave) -> no per-step LDS weight reads,
//     no bank conflicts, and each wave owns full K=512 for its 32 cols
//     (wave = gate) -> no cross-wave K-reduction, tiny gate-exchange LDS only
//   - h loads: inline-asm global_load_dwordx4 sc0 sc1 (L1+L2 bypass; plain
//     bf16 data, flag guarantees no tearing window) -> minimal request count
//   - out (fp32, HBM) stores issued AFTER the flag: HBM ack drains during
//     the next step's poll instead of on the pre-flag barrier
// ---------------------------------------------------------------------------

typedef __attribute__((ext_vector_type(8))) short short8;
typedef __attribute__((ext_vector_type(4))) float f32x4;
typedef __attribute__((ext_vector_type(4))) unsigned int u32x4;

#define T_STEPS 2048

__device__ __forceinline__ unsigned short f2bf(float f) {
  unsigned int x = __float_as_uint(f);
  x += 0x7fffu + ((x >> 16) & 1u);   // RNE
  return (unsigned short)(x >> 16);
}
__device__ __forceinline__ float bf2f(unsigned short u) {
  return __uint_as_float(((unsigned int)u) << 16);
}
// async global->LDS, 16B per lane; lds base must be wave-uniform.
__device__ __forceinline__ void gl2lds16(const void* g, void* lds) {
  __builtin_amdgcn_global_load_lds(
      (const __attribute__((address_space(1))) void*)(uintptr_t)g,
      (__attribute__((address_space(3))) void*)(unsigned int)(uintptr_t)lds,
      16, 0, 0);
}

// --------------------------- phase 0: casts/packs ---------------------------

__global__ __launch_bounds__(256) void cast_x_kernel(
    const float* __restrict__ X, unsigned short* __restrict__ Xb) {
  long long i = ((long long)blockIdx.x * 256 + threadIdx.x) * 8;
  float4 a = *(const float4*)(X + i);
  float4 b = *(const float4*)(X + i + 4);
  union { short8 v; unsigned short u[8]; } o;
  o.u[0] = f2bf(a.x); o.u[1] = f2bf(a.y); o.u[2] = f2bf(a.z); o.u[3] = f2bf(a.w);
  o.u[4] = f2bf(b.x); o.u[5] = f2bf(b.y); o.u[6] = f2bf(b.z); o.u[7] = f2bf(b.w);
  *(short8*)(Xb + i) = o.v;
}

// Wt[n][k] = W_gate(n/512)[k][n%512]  (transposed, bf16)  n in [0,2048)
__global__ __launch_bounds__(256) void pack_w_kernel(
    const float* __restrict__ Wf, const float* __restrict__ Wi,
    const float* __restrict__ Wo, const float* __restrict__ Wc,
    unsigned short* __restrict__ Wt) {
  int n = blockIdx.x;
  int g = n >> 9, h = n & 511;
  const float* W = (g == 0) ? Wf : (g == 1) ? Wi : (g == 2) ? Wo : Wc;
  for (int k = threadIdx.x; k < 512; k += 256)
    Wt[(size_t)n * 512 + k] = f2bf(W[(size_t)k * 512 + h]);
}

// hbuf: u32[2][64][256] (bf16 pairs), flags: int[64]
__global__ __launch_bounds__(256) void init_kernel(unsigned int* hbuf, int* flags) {
  int i = blockIdx.x * 256 + threadIdx.x;
  if (i < 2 * 64 * 256) hbuf[i] = 0u;
  if (i < 64) flags[i] = 0;
}

// --------------------------- phase 1: input GEMM ---------------------------
// A [131072,512] bf16 row-major; Bt [2048,512] bf16 (B transposed);
// C [131072,2048] bf16. 128x128 tile, BK=64, 4 waves in 2x2, 4x4 MFMA each.
__global__ __launch_bounds__(256) void gemm_xg_kernel(
    const unsigned short* __restrict__ A, const unsigned short* __restrict__ Bt,
    unsigned short* __restrict__ C) {
  __shared__ unsigned short As[128 * 64];
  __shared__ unsigned short Bs[128 * 64];
  const int tid = threadIdx.x;
  const int lane = tid & 63, wave = tid >> 6;
  const int bm = blockIdx.x, bn = blockIdx.y;
  const int wm = (wave & 1) * 64, wn = (wave >> 1) * 64;

  f32x4 acc[4][4];
#pragma unroll
  for (int i = 0; i < 4; ++i)
#pragma unroll
    for (int j = 0; j < 4; ++j) acc[i][j] = (f32x4){0.f, 0.f, 0.f, 0.f};

  for (int kt = 0; kt < 512; kt += 64) {
    __syncthreads();  // previous compute done before LDS overwrite
#pragma unroll
    for (int r = 0; r < 4; ++r) {
      int chunk = r * 256 + tid;          // [0,1024): row=chunk>>3, c8=chunk&7
      int row = chunk >> 3, c8 = chunk & 7;
      gl2lds16(A + ((size_t)(bm * 128 + row) * 512 + kt + c8 * 8),
               (void*)(As + (size_t)(r * 256 + wave * 64) * 8));
      gl2lds16(Bt + ((size_t)(bn * 128 + row) * 512 + kt + c8 * 8),
               (void*)(Bs + (size_t)(r * 256 + wave * 64) * 8));
    }
    __syncthreads();  // staging complete (vmcnt drained by barrier)
#pragma unroll
    for (int kc = 0; kc < 64; kc += 32) {
      const int ko = kc + (lane >> 4) * 8;
      short8 av[4], bv[4];
#pragma unroll
      for (int mt = 0; mt < 4; ++mt)
        av[mt] = *(const short8*)(As + (wm + mt * 16 + (lane & 15)) * 64 + ko);
#pragma unroll
      for (int nt = 0; nt < 4; ++nt)
        bv[nt] = *(const short8*)(Bs + (wn + nt * 16 + (lane & 15)) * 64 + ko);
#pragma unroll
      for (int mt = 0; mt < 4; ++mt)
#pragma unroll
        for (int nt = 0; nt < 4; ++nt)
          acc[mt][nt] = __builtin_amdgcn_mfma_f32_16x16x32_bf16(
              av[mt], bv[nt], acc[mt][nt], 0, 0, 0);
    }
  }
  const int q = lane >> 4, cidx = lane & 15;
#pragma unroll
  for (int mt = 0; mt < 4; ++mt)
#pragma unroll
    for (int nt = 0; nt < 4; ++nt)
#pragma unroll
      for (int r = 0; r < 4; ++r) {
        int row = wm + mt * 16 + q * 4 + r;  // C/D: col=lane&15, row=quad*4+reg
        int col = wn + nt * 16 + cidx;
        C[(size_t)(bm * 128 + row) * 2048 + bn * 128 + col] = f2bf(acc[mt][nt][r]);
      }
}

// --------------------------- phase 2: recurrence ---------------------------
// grid 64 = GB(4) x GHW(16). WG (gb,gh): batches gb*16..+16, hidden gh*32..+32.
// Wave w = gate w: owns 32 gate-cols (2 MFMA n-tiles) x K=512, weights in
// 128 VGPRs. Per step: poll 1 flag line -> barrier -> 16x dwordx4 h loads
// (sc0 sc1) + 32 MFMAs -> gate-exchange via 8.5KB LDS -> activation (256
// threads x 2 cols) -> h store (atomic, agent) -> barrier(drain) -> flag ->
// out stores (drain overlaps next poll).
__global__ __launch_bounds__(256, 1) void lstm_rec_kernel(
    const unsigned short* __restrict__ Xg,   // [T*64][2048] bf16
    const unsigned short* __restrict__ Wht,  // [2048][512] bf16 (row n = g*512+h)
    const float* __restrict__ b_f, const float* __restrict__ b_i,
    const float* __restrict__ b_o, const float* __restrict__ b_c,
    float* __restrict__ out, unsigned int* hbuf, int* flags) {
  const int tid = threadIdx.x;
  const int lane = tid & 63, wave = tid >> 6;
  const int gb = blockIdx.x >> 4;
  const int gh = blockIdx.x & 15;
  const int m = lane & 15, quad = lane >> 4;

  __shared__ float Glds[4][16][34];  // [gate][batch][col], +2 pad

  // ---- weight preload: wave w -> gate w, cols gh*32..+32, K=512 ----
  short8 bw0[16], bw1[16];
  {
    const unsigned short* wb = Wht + ((size_t)wave * 512 + gh * 32) * 512;
#pragma unroll
    for (int s = 0; s < 16; ++s) {
      bw0[s] = *(const short8*)(wb + (size_t)m * 512 + s * 32 + quad * 8);
      bw1[s] = *(const short8*)(wb + (size_t)(16 + m) * 512 + s * 32 + quad * 8);
    }
  }

  // activation-side per-thread constants: b = tid>>4, col pair p = tid&15
  const int b = tid >> 4, p = tid & 15;
  const int j0 = gh * 32 + 2 * p;
  const float2 bf_f = *(const float2*)(b_f + j0);
  const float2 bf_i = *(const float2*)(b_i + j0);
  const float2 bf_o = *(const float2*)(b_o + j0);
  const float2 bf_c = *(const float2*)(b_c + j0);
  float c0 = 0.f, c1 = 0.f;

  const int myflag = gb * 16 + gh;

  for (int t = 0; t < T_STEPS; ++t) {
    // Xg prefetch (plain loads, HBM): independent of h_t, runway = poll
    unsigned int xgw0, xgw1, xgw2, xgw3;
    {
      const unsigned int* xr =
          (const unsigned int*)(Xg + ((size_t)t * 64 + gb * 16 + b) * 2048) +
          gh * 16 + p;
      xgw0 = xr[0]; xgw1 = xr[256]; xgw2 = xr[512]; xgw3 = xr[768];
    }
    if (t > 0) {
      if (tid < 16) {
        const int* fp = flags + gb * 16 + tid;   // one 64B line per group
        while (__hip_atomic_load(fp, __ATOMIC_RELAXED,
                                 __HIP_MEMORY_SCOPE_AGENT) < t) {}
      }
      __syncthreads();
      __builtin_amdgcn_fence(__ATOMIC_ACQUIRE, "workgroup");  // compiler order
    }
    // ---- h_t loads: 16 x dwordx4, L1+L2 bypass (coherent read from L3).
    // Plain (non-atomic) is safe: words are only read after the producer's
    // flag, so no torn/mid-update observation is possible.
    const char* hq = (const char*)hbuf + (size_t)(t & 1) * 65536 +
                     (size_t)(gb * 16 + m) * 1024 + (size_t)quad * 16;
    u32x4 hv[16];
#pragma unroll
    for (int s = 0; s < 16; ++s)
      asm volatile("global_load_dwordx4 %0, %1, off sc0 sc1"
                   : "=&v"(hv[s]) : "v"(hq + s * 64) : "memory");
    asm volatile("s_waitcnt vmcnt(0)" ::: "memory");
    __builtin_amdgcn_sched_barrier(0);  // rule #18: pin MFMAs after the wait

    f32x4 acc0 = {0.f, 0.f, 0.f, 0.f}, acc1 = {0.f, 0.f, 0.f, 0.f};
#pragma unroll
    for (int s = 0; s < 16; ++s) {
      union { u32x4 u; short8 v; } au;
      au.u = hv[s];
      acc0 = __builtin_amdgcn_mfma_f32_16x16x32_bf16(au.v, bw0[s], acc0, 0, 0, 0);
      acc1 = __builtin_amdgcn_mfma_f32_16x16x32_bf16(au.v, bw1[s], acc1, 0, 0, 0);
    }
    // gate exchange: wave w's full gates -> Glds[w]
#pragma unroll
    for (int r = 0; r < 4; ++r) {
      Glds[wave][quad * 4 + r][m] = acc0[r];
      Glds[wave][quad * 4 + r][16 + m] = acc1[r];
    }
    __syncthreads();
    // ---- activation: every thread handles (batch b, cols j0, j0+1) ----
    float2 vf = *(const float2*)&Glds[0][b][2 * p];
    float2 vi = *(const float2*)&Glds[1][b][2 * p];
    float2 vo = *(const float2*)&Glds[2][b][2 * p];
    float2 vc = *(const float2*)&Glds[3][b][2 * p];
    float gf0 = vf.x + bf_f.x + bf2f((unsigned short)(xgw0 & 0xffff));
    float gf1 = vf.y + bf_f.y + bf2f((unsigned short)(xgw0 >> 16));
    float gi0 = vi.x + bf_i.x + bf2f((unsigned short)(xgw1 & 0xffff));
    float gi1 = vi.y + bf_i.y + bf2f((unsigned short)(xgw1 >> 16));
    float go0 = vo.x + bf_o.x + bf2f((unsigned short)(xgw2 & 0xffff));
    float go1 = vo.y + bf_o.y + bf2f((unsigned short)(xgw2 >> 16));
    float gc0 = vc.x + bf_c.x + bf2f((unsigned short)(xgw3 & 0xffff));
    float gc1 = vc.y + bf_c.y + bf2f((unsigned short)(xgw3 >> 16));
    float f0 = 1.f / (1.f + __expf(-gf0)), f1 = 1.f / (1.f + __expf(-gf1));
    float i0 = 1.f / (1.f + __expf(-gi0)), i1 = 1.f / (1.f + __expf(-gi1));
    float o0 = 1.f / (1.f + __expf(-go0)), o1 = 1.f / (1.f + __expf(-go1));
    float ch0 = 1.f - 2.f / (1.f + __expf(2.f * gc0));   // tanh
    float ch1 = 1.f - 2.f / (1.f + __expf(2.f * gc1));
    c0 = f0 * c0 + i0 * ch0;
    c1 = f1 * c1 + i1 * ch1;
    float h0 = o0 * (1.f - 2.f / (1.f + __expf(2.f * c0)));
    float h1 = o1 * (1.f - 2.f / (1.f + __expf(2.f * c1)));
    // h store first (only this must drain before the flag)
    unsigned int hword = ((unsigned int)f2bf(h1) << 16) | (unsigned int)f2bf(h0);
    __hip_atomic_store(hbuf + (size_t)((t + 1) & 1) * 16384 +
                           (size_t)(gb * 16 + b) * 256 + gh * 16 + p,
                       hword, __ATOMIC_RELAXED, __HIP_MEMORY_SCOPE_AGENT);
    __syncthreads();  // drains all waves' vmcnt -> h visible at L3
    __builtin_amdgcn_fence(__ATOMIC_RELEASE, "workgroup");  // compiler order
    if (tid == 0)
      __hip_atomic_store(flags + myflag, t + 1, __ATOMIC_RELAXED,
                         __HIP_MEMORY_SCOPE_AGENT);
    // out stores AFTER the flag: HBM ack overlaps the next step's poll
    float2 h2; h2.x = h0; h2.y = h1;
    *(float2*)(out + ((size_t)t * 64 + gb * 16 + b) * 512 + j0) = h2;
    if (t == T_STEPS - 1) {
      size_t base = (size_t)T_STEPS * 64 * 512;
      *(float2*)(out + base + (size_t)(gb * 16 + b) * 512 + j0) = h2;
      float2 c2; c2.x = c0; c2.y = c1;
      *(float2*)(out + base + 64 * 512 + (size_t)(gb * 16 + b) * 512 + j0) = c2;
    }
  }
}

// ------------------------------- launch ------------------------------------

extern "C" void kernel_launch(void* const* d_in, const int* in_sizes, int n_in,
                              void* d_out, int out_size, void* d_ws, size_t ws_size,
                              hipStream_t stream) {
  const float* X    = (const float*)d_in[0];
  const float* W_xf = (const float*)d_in[1];
  const float* W_hf = (const float*)d_in[2];
  const float* b_f  = (const float*)d_in[3];
  const float* W_xi = (const float*)d_in[4];
  const float* W_hi = (const float*)d_in[5];
  const float* b_i  = (const float*)d_in[6];
  const float* W_xo = (const float*)d_in[7];
  const float* W_ho = (const float*)d_in[8];
  const float* b_o  = (const float*)d_in[9];
  const float* W_xc = (const float*)d_in[10];
  const float* W_hc = (const float*)d_in[11];
  const float* b_c  = (const float*)d_in[12];
  float* out = (float*)d_out;

  char* ws = (char*)d_ws;
  unsigned short* Xb   = (unsigned short*)(ws + 0LL);           // 134,217,728 B (dead after gemm)
  unsigned short* Xg   = (unsigned short*)(ws + 134217728LL);   // 536,870,912 B
  unsigned short* Wxt  = (unsigned short*)(ws + 671088640LL);   //   2,097,152 B
  unsigned short* Wht  = (unsigned short*)(ws + 673185792LL);   //   2,097,152 B
  unsigned int* hbuf   = (unsigned int*)(ws + 0LL);             //     131,072 B (reuses Xb region)
  int* flags           = (int*)(ws + 131072LL);                 //         256 B

  cast_x_kernel<<<dim3(32768), dim3(256), 0, stream>>>(X, Xb);
  pack_w_kernel<<<dim3(2048), dim3(256), 0, stream>>>(W_xf, W_xi, W_xo, W_xc, Wxt);
  pack_w_kernel<<<dim3(2048), dim3(256), 0, stream>>>(W_hf, W_hi, W_ho, W_hc, Wht);
  gemm_xg_kernel<<<dim3(1024, 16), dim3(256), 0, stream>>>(Xb, Wxt, Xg);
  // hbuf/flags alias Xb: init only after the GEMM has consumed Xb.
  init_kernel<<<dim3(128), dim3(256), 0, stream>>>(hbuf, flags);
  lstm_rec_kernel<<<dim3(64), dim3(256), 0, stream>>>(Xg, Wht, b_f, b_i, b_o, b_c,
                                                      out, hbuf, flags);
}

// Round 5
// 8493.501 us; speedup vs baseline: 2.2555x; 1.0136x over previous
//
#include <hip/hip_runtime.h>
#include <stdint.h>

// ---------------------------------------------------------------------------
// LSTM forward, T=2048 B=64 I=H=512.
// Phase 1: Xg = X @ [W_xf|W_xi|W_xo|W_xc]  (bf16 MFMA GEMM, m97-style tile)
// Phase 2: persistent recurrence, 64 WGs = 4 batch-groups x 16 hidden-groups.
//   Round-4 structure (verified correct) + spill fix:
//   - ROUND-5 FIX: round 4 reported VGPR_Count=120 < the 128 weight VGPRs the
//     design needs -> RA spilled stationary weights to scratch and re-read
//     them EVERY step (the 7710us regression). Fix: (a) amdgpu_waves_per_eu
//     (1,1) so RA stops chasing 4-waves/EU occupancy, (b) weights laundered
//     into AGPRs ("+a" asm) -- gfx950 MFMA reads B-operands from AGPR class
//     directly; 128 AGPR + ~110 VGPR fits the 512 unified budget with room.
//   - flags: 16 per group in ONE cacheline -> poll = 1 coalesced L3 request
//   - wave = gate: owns 32 gate-cols x K=512 -> no cross-wave K-reduction
//   - h loads: global_load_dwordx4 sc0 sc1 (L1+L2 bypass, coherent from L3)
//   - out fp32 stores issued AFTER the flag (HBM ack overlaps next poll)
// ---------------------------------------------------------------------------

typedef __attribute__((ext_vector_type(8))) short short8;
typedef __attribute__((ext_vector_type(4))) float f32x4;
typedef __attribute__((ext_vector_type(4))) unsigned int u32x4;

#define T_STEPS 2048

__device__ __forceinline__ unsigned short f2bf(float f) {
  unsigned int x = __float_as_uint(f);
  x += 0x7fffu + ((x >> 16) & 1u);   // RNE
  return (unsigned short)(x >> 16);
}
__device__ __forceinline__ float bf2f(unsigned short u) {
  return __uint_as_float(((unsigned int)u) << 16);
}
// async global->LDS, 16B per lane; lds base must be wave-uniform.
__device__ __forceinline__ void gl2lds16(const void* g, void* lds) {
  __builtin_amdgcn_global_load_lds(
      (const __attribute__((address_space(1))) void*)(uintptr_t)g,
      (__attribute__((address_space(3))) void*)(unsigned int)(uintptr_t)lds,
      16, 0, 0);
}

// --------------------------- phase 0: casts/packs ---------------------------

__global__ __launch_bounds__(256) void cast_x_kernel(
    const float* __restrict__ X, unsigned short* __restrict__ Xb) {
  long long i = ((long long)blockIdx.x * 256 + threadIdx.x) * 8;
  float4 a = *(const float4*)(X + i);
  float4 b = *(const float4*)(X + i + 4);
  union { short8 v; unsigned short u[8]; } o;
  o.u[0] = f2bf(a.x); o.u[1] = f2bf(a.y); o.u[2] = f2bf(a.z); o.u[3] = f2bf(a.w);
  o.u[4] = f2bf(b.x); o.u[5] = f2bf(b.y); o.u[6] = f2bf(b.z); o.u[7] = f2bf(b.w);
  *(short8*)(Xb + i) = o.v;
}

// Wt[n][k] = W_gate(n/512)[k][n%512]  (transposed, bf16)  n in [0,2048)
__global__ __launch_bounds__(256) void pack_w_kernel(
    const float* __restrict__ Wf, const float* __restrict__ Wi,
    const float* __restrict__ Wo, const float* __restrict__ Wc,
    unsigned short* __restrict__ Wt) {
  int n = blockIdx.x;
  int g = n >> 9, h = n & 511;
  const float* W = (g == 0) ? Wf : (g == 1) ? Wi : (g == 2) ? Wo : Wc;
  for (int k = threadIdx.x; k < 512; k += 256)
    Wt[(size_t)n * 512 + k] = f2bf(W[(size_t)k * 512 + h]);
}

// hbuf: u32[2][64][256] (bf16 pairs), flags: int[64]
__global__ __launch_bounds__(256) void init_kernel(unsigned int* hbuf, int* flags) {
  int i = blockIdx.x * 256 + threadIdx.x;
  if (i < 2 * 64 * 256) hbuf[i] = 0u;
  if (i < 64) flags[i] = 0;
}

// --------------------------- phase 1: input GEMM ---------------------------
// A [131072,512] bf16 row-major; Bt [2048,512] bf16 (B transposed);
// C [131072,2048] bf16. 128x128 tile, BK=64, 4 waves in 2x2, 4x4 MFMA each.
__global__ __launch_bounds__(256) void gemm_xg_kernel(
    const unsigned short* __restrict__ A, const unsigned short* __restrict__ Bt,
    unsigned short* __restrict__ C) {
  __shared__ unsigned short As[128 * 64];
  __shared__ unsigned short Bs[128 * 64];
  const int tid = threadIdx.x;
  const int lane = tid & 63, wave = tid >> 6;
  const int bm = blockIdx.x, bn = blockIdx.y;
  const int wm = (wave & 1) * 64, wn = (wave >> 1) * 64;

  f32x4 acc[4][4];
#pragma unroll
  for (int i = 0; i < 4; ++i)
#pragma unroll
    for (int j = 0; j < 4; ++j) acc[i][j] = (f32x4){0.f, 0.f, 0.f, 0.f};

  for (int kt = 0; kt < 512; kt += 64) {
    __syncthreads();  // previous compute done before LDS overwrite
#pragma unroll
    for (int r = 0; r < 4; ++r) {
      int chunk = r * 256 + tid;          // [0,1024): row=chunk>>3, c8=chunk&7
      int row = chunk >> 3, c8 = chunk & 7;
      gl2lds16(A + ((size_t)(bm * 128 + row) * 512 + kt + c8 * 8),
               (void*)(As + (size_t)(r * 256 + wave * 64) * 8));
      gl2lds16(Bt + ((size_t)(bn * 128 + row) * 512 + kt + c8 * 8),
               (void*)(Bs + (size_t)(r * 256 + wave * 64) * 8));
    }
    __syncthreads();  // staging complete (vmcnt drained by barrier)
#pragma unroll
    for (int kc = 0; kc < 64; kc += 32) {
      const int ko = kc + (lane >> 4) * 8;
      short8 av[4], bv[4];
#pragma unroll
      for (int mt = 0; mt < 4; ++mt)
        av[mt] = *(const short8*)(As + (wm + mt * 16 + (lane & 15)) * 64 + ko);
#pragma unroll
      for (int nt = 0; nt < 4; ++nt)
        bv[nt] = *(const short8*)(Bs + (wn + nt * 16 + (lane & 15)) * 64 + ko);
#pragma unroll
      for (int mt = 0; mt < 4; ++mt)
#pragma unroll
        for (int nt = 0; nt < 4; ++nt)
          acc[mt][nt] = __builtin_amdgcn_mfma_f32_16x16x32_bf16(
              av[mt], bv[nt], acc[mt][nt], 0, 0, 0);
    }
  }
  const int q = lane >> 4, cidx = lane & 15;
#pragma unroll
  for (int mt = 0; mt < 4; ++mt)
#pragma unroll
    for (int nt = 0; nt < 4; ++nt)
#pragma unroll
      for (int r = 0; r < 4; ++r) {
        int row = wm + mt * 16 + q * 4 + r;  // C/D: col=lane&15, row=quad*4+reg
        int col = wn + nt * 16 + cidx;
        C[(size_t)(bm * 128 + row) * 2048 + bn * 128 + col] = f2bf(acc[mt][nt][r]);
      }
}

// --------------------------- phase 2: recurrence ---------------------------
// grid 64 = GB(4) x GHW(16). WG (gb,gh): batches gb*16..+16, hidden gh*32..+32.
// Wave w = gate w: owns 32 gate-cols (2 MFMA n-tiles) x K=512, weights in
// 128 AGPRs (stationary, spill-proof). Per step: poll 1 flag line -> barrier
// -> 16x dwordx4 h loads (sc0 sc1) + 32 MFMAs -> gate exchange via 8.5KB LDS
// -> activation (256 threads x 2 cols) -> h store (atomic, agent) ->
// barrier(drain) -> flag -> out stores (drain overlaps next poll).
__global__ __launch_bounds__(256)
__attribute__((amdgpu_waves_per_eu(1, 1)))
void lstm_rec_kernel(
    const unsigned short* __restrict__ Xg,   // [T*64][2048] bf16
    const unsigned short* __restrict__ Wht,  // [2048][512] bf16 (row n = g*512+h)
    const float* __restrict__ b_f, const float* __restrict__ b_i,
    const float* __restrict__ b_o, const float* __restrict__ b_c,
    float* __restrict__ out, unsigned int* hbuf, int* flags) {
  const int tid = threadIdx.x;
  const int lane = tid & 63, wave = tid >> 6;
  const int gb = blockIdx.x >> 4;
  const int gh = blockIdx.x & 15;
  const int m = lane & 15, quad = lane >> 4;

  __shared__ float Glds[4][16][34];  // [gate][batch][col], +2 pad

  // ---- weight preload: wave w -> gate w, cols gh*32..+32, K=512 ----
  short8 bw0[16], bw1[16];
  {
    const unsigned short* wb = Wht + ((size_t)wave * 512 + gh * 32) * 512;
#pragma unroll
    for (int s = 0; s < 16; ++s) {
      bw0[s] = *(const short8*)(wb + (size_t)m * 512 + s * 32 + quad * 8);
      bw1[s] = *(const short8*)(wb + (size_t)(16 + m) * 512 + s * 32 + quad * 8);
    }
  }
  // Pin the stationary weights in the AGPR file: MFMA consumes AGPR operands
  // directly on gfx950 (unified RF), and the AGPR side has zero other
  // pressure -> RA cannot be tempted to spill them to scratch (round-4 bug).
#pragma unroll
  for (int s = 0; s < 16; ++s)
    asm volatile("" : "+a"(bw0[s]), "+a"(bw1[s]));

  // activation-side per-thread constants: b = tid>>4, col pair p = tid&15
  const int b = tid >> 4, p = tid & 15;
  const int j0 = gh * 32 + 2 * p;
  const float2 bf_f = *(const float2*)(b_f + j0);
  const float2 bf_i = *(const float2*)(b_i + j0);
  const float2 bf_o = *(const float2*)(b_o + j0);
  const float2 bf_c = *(const float2*)(b_c + j0);
  float c0 = 0.f, c1 = 0.f;

  const int myflag = gb * 16 + gh;

  for (int t = 0; t < T_STEPS; ++t) {
    // Xg prefetch (plain loads, HBM): independent of h_t, runway = poll
    unsigned int xgw0, xgw1, xgw2, xgw3;
    {
      const unsigned int* xr =
          (const unsigned int*)(Xg + ((size_t)t * 64 + gb * 16 + b) * 2048) +
          gh * 16 + p;
      xgw0 = xr[0]; xgw1 = xr[256]; xgw2 = xr[512]; xgw3 = xr[768];
    }
    if (t > 0) {
      if (tid < 16) {
        const int* fp = flags + gb * 16 + tid;   // one 64B line per group
        while (__hip_atomic_load(fp, __ATOMIC_RELAXED,
                                 __HIP_MEMORY_SCOPE_AGENT) < t) {}
      }
      __syncthreads();
      __builtin_amdgcn_fence(__ATOMIC_ACQUIRE, "workgroup");  // compiler order
    }
    // ---- h_t loads: 16 x dwordx4, L1+L2 bypass (coherent read from L3).
    // Plain (non-atomic) is safe: words are only read after the producer's
    // flag, so no torn/mid-update observation is possible.
    const char* hq = (const char*)hbuf + (size_t)(t & 1) * 65536 +
                     (size_t)(gb * 16 + m) * 1024 + (size_t)quad * 16;
    u32x4 hv[16];
#pragma unroll
    for (int s = 0; s < 16; ++s)
      asm volatile("global_load_dwordx4 %0, %1, off sc0 sc1"
                   : "=&v"(hv[s]) : "v"(hq + s * 64) : "memory");
    asm volatile("s_waitcnt vmcnt(0)" ::: "memory");
    __builtin_amdgcn_sched_barrier(0);  // rule #18: pin MFMAs after the wait

    f32x4 acc0 = {0.f, 0.f, 0.f, 0.f}, acc1 = {0.f, 0.f, 0.f, 0.f};
#pragma unroll
    for (int s = 0; s < 16; ++s) {
      union { u32x4 u; short8 v; } au;
      au.u = hv[s];
      acc0 = __builtin_amdgcn_mfma_f32_16x16x32_bf16(au.v, bw0[s], acc0, 0, 0, 0);
      acc1 = __builtin_amdgcn_mfma_f32_16x16x32_bf16(au.v, bw1[s], acc1, 0, 0, 0);
    }
    // gate exchange: wave w's full gates -> Glds[w]
#pragma unroll
    for (int r = 0; r < 4; ++r) {
      Glds[wave][quad * 4 + r][m] = acc0[r];
      Glds[wave][quad * 4 + r][16 + m] = acc1[r];
    }
    __syncthreads();
    // ---- activation: every thread handles (batch b, cols j0, j0+1) ----
    float2 vf = *(const float2*)&Glds[0][b][2 * p];
    float2 vi = *(const float2*)&Glds[1][b][2 * p];
    float2 vo = *(const float2*)&Glds[2][b][2 * p];
    float2 vc = *(const float2*)&Glds[3][b][2 * p];
    float gf0 = vf.x + bf_f.x + bf2f((unsigned short)(xgw0 & 0xffff));
    float gf1 = vf.y + bf_f.y + bf2f((unsigned short)(xgw0 >> 16));
    float gi0 = vi.x + bf_i.x + bf2f((unsigned short)(xgw1 & 0xffff));
    float gi1 = vi.y + bf_i.y + bf2f((unsigned short)(xgw1 >> 16));
    float go0 = vo.x + bf_o.x + bf2f((unsigned short)(xgw2 & 0xffff));
    float go1 = vo.y + bf_o.y + bf2f((unsigned short)(xgw2 >> 16));
    float gc0 = vc.x + bf_c.x + bf2f((unsigned short)(xgw3 & 0xffff));
    float gc1 = vc.y + bf_c.y + bf2f((unsigned short)(xgw3 >> 16));
    float f0 = 1.f / (1.f + __expf(-gf0)), f1 = 1.f / (1.f + __expf(-gf1));
    float i0 = 1.f / (1.f + __expf(-gi0)), i1 = 1.f / (1.f + __expf(-gi1));
    float o0 = 1.f / (1.f + __expf(-go0)), o1 = 1.f / (1.f + __expf(-go1));
    float ch0 = 1.f - 2.f / (1.f + __expf(2.f * gc0));   // tanh
    float ch1 = 1.f - 2.f / (1.f + __expf(2.f * gc1));
    c0 = f0 * c0 + i0 * ch0;
    c1 = f1 * c1 + i1 * ch1;
    float h0 = o0 * (1.f - 2.f / (1.f + __expf(2.f * c0)));
    float h1 = o1 * (1.f - 2.f / (1.f + __expf(2.f * c1)));
    // h store first (only this must drain before the flag)
    unsigned int hword = ((unsigned int)f2bf(h1) << 16) | (unsigned int)f2bf(h0);
    __hip_atomic_store(hbuf + (size_t)((t + 1) & 1) * 16384 +
                           (size_t)(gb * 16 + b) * 256 + gh * 16 + p,
                       hword, __ATOMIC_RELAXED, __HIP_MEMORY_SCOPE_AGENT);
    __syncthreads();  // drains all waves' vmcnt -> h visible at L3
    __builtin_amdgcn_fence(__ATOMIC_RELEASE, "workgroup");  // compiler order
    if (tid == 0)
      __hip_atomic_store(flags + myflag, t + 1, __ATOMIC_RELAXED,
                         __HIP_MEMORY_SCOPE_AGENT);
    // out stores AFTER the flag: HBM ack overlaps the next step's poll
    float2 h2; h2.x = h0; h2.y = h1;
    *(float2*)(out + ((size_t)t * 64 + gb * 16 + b) * 512 + j0) = h2;
    if (t == T_STEPS - 1) {
      size_t base = (size_t)T_STEPS * 64 * 512;
      *(float2*)(out + base + (size_t)(gb * 16 + b) * 512 + j0) = h2;
      float2 c2; c2.x = c0; c2.y = c1;
      *(float2*)(out + base + 64 * 512 + (size_t)(gb * 16 + b) * 512 + j0) = c2;
    }
  }
}

// ------------------------------- launch ------------------------------------

extern "C" void kernel_launch(void* const* d_in, const int* in_sizes, int n_in,
                              void* d_out, int out_size, void* d_ws, size_t ws_size,
                              hipStream_t stream) {
  const float* X    = (const float*)d_in[0];
  const float* W_xf = (const float*)d_in[1];
  const float* W_hf = (const float*)d_in[2];
  const float* b_f  = (const float*)d_in[3];
  const float* W_xi = (const float*)d_in[4];
  const float* W_hi = (const float*)d_in[5];
  const float* b_i  = (const float*)d_in[6];
  const float* W_xo = (const float*)d_in[7];
  const float* W_ho = (const float*)d_in[8];
  const float* b_o  = (const float*)d_in[9];
  const float* W_xc = (const float*)d_in[10];
  const float* W_hc = (const float*)d_in[11];
  const float* b_c  = (const float*)d_in[12];
  float* out = (float*)d_out;

  char* ws = (char*)d_ws;
  unsigned short* Xb   = (unsigned short*)(ws + 0LL);           // 134,217,728 B (dead after gemm)
  unsigned short* Xg   = (unsigned short*)(ws + 134217728LL);   // 536,870,912 B
  unsigned short* Wxt  = (unsigned short*)(ws + 671088640LL);   //   2,097,152 B
  unsigned short* Wht  = (unsigned short*)(ws + 673185792LL);   //   2,097,152 B
  unsigned int* hbuf   = (unsigned int*)(ws + 0LL);             //     131,072 B (reuses Xb region)
  int* flags           = (int*)(ws + 131072LL);                 //         256 B

  cast_x_kernel<<<dim3(32768), dim3(256), 0, stream>>>(X, Xb);
  pack_w_kernel<<<dim3(2048), dim3(256), 0, stream>>>(W_xf, W_xi, W_xo, W_xc, Wxt);
  pack_w_kernel<<<dim3(2048), dim3(256), 0, stream>>>(W_hf, W_hi, W_ho, W_hc, Wht);
  gemm_xg_kernel<<<dim3(1024, 16), dim3(256), 0, stream>>>(Xb, Wxt, Xg);
  // hbuf/flags alias Xb: init only after the GEMM has consumed Xb.
  init_kernel<<<dim3(128), dim3(256), 0, stream>>>(hbuf, flags);
  lstm_rec_kernel<<<dim3(64), dim3(256), 0, stream>>>(Xg, Wht, b_f, b_i, b_o, b_c,
                                                      out, hbuf, flags);
}